// Round 12
// baseline (321.648 us; speedup 1.0000x reference)
//
#include <hip/hip_runtime.h>

#define BSZ 32
#define SLEN 512
#define CLEN 20
#define DMOD 256
#define NH 4
#define HDIM 64

typedef _Float16 half8 __attribute__((ext_vector_type(8)));
typedef _Float16 half4 __attribute__((ext_vector_type(4)));
typedef float float4v __attribute__((ext_vector_type(4)));

#define MFMA16(a, b, c) __builtin_amdgcn_mfma_f32_16x16x32_f16(a, b, c, 0, 0, 0)
// padded half8 index: groups of 16 half8 get stride 17 (breaks 256B-stride conflicts)
#define PG(fi) ((((fi) >> 4) * 17) + ((fi) & 15))

// ---------------- embedding sum + positional encoding -> fp16 ------------------
__global__ __launch_bounds__(256) void k_embed(
    const int* __restrict__ seqs, const int* __restrict__ lengths,
    const float* __restrict__ emb, const float* __restrict__ bias,
    const float* __restrict__ pe, _Float16* __restrict__ x) {
  const int row0 = blockIdx.x * 4;
  const int sub = threadIdx.x >> 6;
  const int lane = threadIdx.x & 63;
  const int row = row0 + sub;
  const int b = row >> 9, s = row & 511;
  __shared__ int codes[4][CLEN];
  if (threadIdx.x < 4 * CLEN)
    codes[threadIdx.x / CLEN][threadIdx.x % CLEN] = seqs[row0 * CLEN + threadIdx.x];
  __syncthreads();
  const int pos = (s < lengths[b]) ? (s + 1) : 0;
  const int d = lane * 4;
  float4 acc = *(const float4*)(bias + d);
  const float4 pv = *(const float4*)(pe + (size_t)pos * DMOD + d);
  acc.x += pv.x; acc.y += pv.y; acc.z += pv.z; acc.w += pv.w;
  #pragma unroll
  for (int c = 0; c < CLEN; ++c) {
    const float4 ev = *(const float4*)(emb + (size_t)codes[sub][c] * DMOD + d);
    acc.x += ev.x; acc.y += ev.y; acc.z += ev.z; acc.w += ev.w;
  }
  half4 hv;
  hv[0] = (_Float16)acc.x; hv[1] = (_Float16)acc.y;
  hv[2] = (_Float16)acc.z; hv[3] = (_Float16)acc.w;
  *(half4*)(x + (size_t)row * DMOD + d) = hv;
}

// ---------------- cast 4 weight matrices [256x256] fp32 -> fp16 ----------------
__global__ __launch_bounds__(256) void k_wsplit(
    const float* __restrict__ W0, const float* __restrict__ W1,
    const float* __restrict__ W2, const float* __restrict__ W3,
    _Float16* __restrict__ wh) {
  const int z = blockIdx.y;
  const float* W = (z == 0) ? W0 : (z == 1) ? W1 : (z == 2) ? W2 : W3;
  const int idx = (blockIdx.x * 256 + threadIdx.x) * 8;
  float v[8];
  *(float4*)v = *(const float4*)(W + idx);
  *(float4*)(v + 4) = *(const float4*)(W + idx + 4);
  half8 h;
  #pragma unroll
  for (int i = 0; i < 8; ++i) h[i] = (_Float16)v[i];
  *(half8*)(wh + (size_t)z * 65536 + idx) = h;
}

// ---------------- bit-pack attention mask: [32,512,512] int -> [32,512,16] u32 ----
__global__ __launch_bounds__(256) void k_maskpack(
    const int* __restrict__ masks, unsigned int* __restrict__ pk) {
  const int bq = blockIdx.x;
  const int wv = threadIdx.x >> 6;
  const int lane = threadIdx.x & 63;
  #pragma unroll
  for (int p = 0; p < 2; ++p) {
    const int chunk = wv + p * 4;
    const int m = masks[(size_t)bq * SLEN + chunk * 64 + lane];
    const unsigned long long bal = __ballot(m != 0);
    if (lane == 0) {
      pk[(size_t)bq * 16 + chunk * 2]     = (unsigned int)bal;
      pk[(size_t)bq * 16 + chunk * 2 + 1] = (unsigned int)(bal >> 32);
    }
  }
}

// ---------------- QKV GEMM: fp16 MFMA, prefetch, vectorized epilogue ------------
__global__ __launch_bounds__(256) void k_gemm_qkv(
    const _Float16* __restrict__ A, const _Float16* __restrict__ Wb,
    _Float16* __restrict__ q, _Float16* __restrict__ k, _Float16* __restrict__ v) {
  const int z = blockIdx.z;
  _Float16* Cb = (z == 0) ? q : (z == 1) ? k : v;
  const _Float16* w_ = Wb + (size_t)z * 65536;
  const int m0 = blockIdx.x * 128;
  const int n0 = blockIdx.y * 128;
  const int tid = threadIdx.x;
  const int lane = tid & 63;
  const int w = tid >> 6;
  const int wm = (w >> 1) * 4;
  const int wn = (w & 1) * 4;
  __shared__ _Float16 smem[8704];               // 17 KB: staging; epilogue reuse
  half8* As = (half8*)(smem);
  half8* Ws = (half8*)(smem + 4096);
  float4v acc[4][4];
  #pragma unroll
  for (int i = 0; i < 4; ++i)
    #pragma unroll
    for (int j = 0; j < 4; ++j)
      acc[i][j] = (float4v){0.f, 0.f, 0.f, 0.f};
  int li_[2]; size_t ga_[2], gw_[2];
  #pragma unroll
  for (int p = 0; p < 2; ++p) {
    const int c = tid + p * 256;
    const int r = c & 127, qd = c >> 7;
    li_[p] = (r >> 4) * 64 + qd * 16 + (r & 15);
    ga_[p] = (size_t)(m0 + r) * DMOD + qd * 8;
    gw_[p] = (size_t)(n0 + r) * DMOD + qd * 8;
  }
  half8 pa[2], pw[2];
  #pragma unroll
  for (int p = 0; p < 2; ++p) {
    pa[p] = *(const half8*)(A + ga_[p]);
    pw[p] = *(const half8*)(w_ + gw_[p]);
  }
  for (int k0 = 0; k0 < DMOD; k0 += 32) {
    #pragma unroll
    for (int p = 0; p < 2; ++p) {
      As[li_[p]] = pa[p];
      Ws[li_[p]] = pw[p];
    }
    __syncthreads();
    if (k0 + 32 < DMOD) {
      #pragma unroll
      for (int p = 0; p < 2; ++p) {
        pa[p] = *(const half8*)(A + ga_[p] + k0 + 32);
        pw[p] = *(const half8*)(w_ + gw_[p] + k0 + 32);
      }
    }
    half8 af[4], wf[4];
    #pragma unroll
    for (int i = 0; i < 4; ++i) {
      af[i] = As[(wm + i) * 64 + lane];
      wf[i] = Ws[(wn + i) * 64 + lane];
    }
    #pragma unroll
    for (int i = 0; i < 4; ++i)
      #pragma unroll
      for (int j = 0; j < 4; ++j)
        acc[i][j] = MFMA16(af[i], wf[j], acc[i][j]);
    __syncthreads();
  }
  const int cr = (lane >> 4) * 4;
  const int cc = lane & 15;
  _Float16* Eh = smem;
  #pragma unroll
  for (int ip = 0; ip < 4; ++ip) {
    #pragma unroll
    for (int j = 0; j < 4; ++j) {
      const int col = (wn + j) * 16 + cc;
      #pragma unroll
      for (int r = 0; r < 4; ++r)
        Eh[((w >> 1) * 16 + cr + r) * 136 + col] = (_Float16)acc[ip][j][r];
    }
    __syncthreads();
    #pragma unroll
    for (int e = 0; e < 2; ++e) {
      const int idx = tid + e * 256;
      const int lr = idx >> 4;
      const int cg = idx & 15;
      const int gr = m0 + (lr >> 4) * 64 + ip * 16 + (lr & 15);
      *(half8*)(Cb + (size_t)gr * DMOD + n0 + cg * 8) =
          *(const half8*)&Eh[lr * 136 + cg * 8];
    }
    __syncthreads();
  }
}

// ---------------- per-bh transpose: v[bh][s][d] -> vt[bh][d][s] -----------------
__global__ __launch_bounds__(256) void k_vt(
    const _Float16* __restrict__ v, _Float16* __restrict__ vt) {
  const int bh = blockIdx.x;
  const size_t off = (size_t)bh * 32768;
  __shared__ _Float16 Th[64][66];
  const int tid = threadIdx.x;
  const int c0 = blockIdx.y * 4;
  for (int c = c0; c < c0 + 4; ++c) {
    const int sc = c * 64;
    #pragma unroll
    for (int p = 0; p < 2; ++p) {
      const int lin = tid + p * 256;
      const int r = lin >> 3, g = lin & 7;
      *(half8*)&Th[r][g * 8] = *(const half8*)(v + off + (size_t)(sc + r) * 64 + g * 8);
    }
    __syncthreads();
    #pragma unroll
    for (int p = 0; p < 2; ++p) {
      const int lin = tid + p * 256;
      const int d = lin >> 3, sg = lin & 7;
      half8 hv;
      #pragma unroll
      for (int j = 0; j < 8; ++j) hv[j] = Th[sg * 8 + j][d];
      *(half8*)(vt + off + (size_t)d * 512 + sc + sg * 8) = hv;
    }
    __syncthreads();
  }
}

// ---------------- FC GEMM (fp32 out + fp16 residual), fp16 MFMA -----------------
__global__ __launch_bounds__(256) void k_gemm_fc(
    const _Float16* __restrict__ A, const _Float16* __restrict__ w_,
    float* __restrict__ C, const _Float16* __restrict__ res) {
  const int m0 = blockIdx.x * 128;
  const int n0 = blockIdx.y * 128;
  const int tid = threadIdx.x;
  const int lane = tid & 63;
  const int w = tid >> 6;
  const int wm = (w >> 1) * 4;
  const int wn = (w & 1) * 4;
  __shared__ half8 As[512], Ws[512];
  float4v acc[4][4];
  #pragma unroll
  for (int i = 0; i < 4; ++i)
    #pragma unroll
    for (int j = 0; j < 4; ++j)
      acc[i][j] = (float4v){0.f, 0.f, 0.f, 0.f};
  int li_[2]; size_t ga_[2], gw_[2];
  #pragma unroll
  for (int p = 0; p < 2; ++p) {
    const int c = tid + p * 256;
    const int r = c & 127, qd = c >> 7;
    li_[p] = (r >> 4) * 64 + qd * 16 + (r & 15);
    ga_[p] = (size_t)(m0 + r) * DMOD + qd * 8;
    gw_[p] = (size_t)(n0 + r) * DMOD + qd * 8;
  }
  half8 pa[2], pw[2];
  #pragma unroll
  for (int p = 0; p < 2; ++p) {
    pa[p] = *(const half8*)(A + ga_[p]);
    pw[p] = *(const half8*)(w_ + gw_[p]);
  }
  for (int k0 = 0; k0 < DMOD; k0 += 32) {
    #pragma unroll
    for (int p = 0; p < 2; ++p) {
      As[li_[p]] = pa[p];
      Ws[li_[p]] = pw[p];
    }
    __syncthreads();
    if (k0 + 32 < DMOD) {
      #pragma unroll
      for (int p = 0; p < 2; ++p) {
        pa[p] = *(const half8*)(A + ga_[p] + k0 + 32);
        pw[p] = *(const half8*)(w_ + gw_[p] + k0 + 32);
      }
    }
    half8 af[4], wf[4];
    #pragma unroll
    for (int i = 0; i < 4; ++i) {
      af[i] = As[(wm + i) * 64 + lane];
      wf[i] = Ws[(wn + i) * 64 + lane];
    }
    #pragma unroll
    for (int i = 0; i < 4; ++i)
      #pragma unroll
      for (int j = 0; j < 4; ++j)
        acc[i][j] = MFMA16(af[i], wf[j], acc[i][j]);
    __syncthreads();
  }
  const int cr = (lane >> 4) * 4;
  const int cc = lane & 15;
  #pragma unroll
  for (int i = 0; i < 4; ++i) {
    const int gm = m0 + (wm + i) * 16 + cr;
    #pragma unroll
    for (int j = 0; j < 4; ++j) {
      const int gc = n0 + (wn + j) * 16 + cc;
      #pragma unroll
      for (int r = 0; r < 4; ++r) {
        const size_t flat = (size_t)(gm + r) * DMOD + gc;
        C[flat] = acc[i][j][r] + (float)res[flat];
      }
    }
  }
}

// ---------------- MFMA attention per (bh, q-tile of 64), fp16 -------------------
// Padded frag-order LDS, Q frags in registers, Q LDS reused for P.
// O epilogue restaged through LDS (Ks region) -> full-cache-line half8 stores.
__global__ __launch_bounds__(256, 4) void k_attn(
    const _Float16* __restrict__ q_, const _Float16* __restrict__ k_,
    const _Float16* __restrict__ vt, const unsigned int* __restrict__ pk,
    _Float16* __restrict__ o) {
  const int bh = blockIdx.x;
  const int q0 = blockIdx.y * 64;
  const size_t bhoff = (size_t)bh * 32768;
  __shared__ half8 QP[544];                     // Q staging, then P
  __shared__ half8 Ks[544], Vs[544];            // Ks reused as O-tile in epilogue
  __shared__ unsigned int Ms[64][2];
  __shared__ float Ps[4][64];
  __shared__ float lsum[64];
  const int tid = threadIdx.x;
  const int w = tid >> 6;
  const int lane = tid & 63;
  const int l15 = lane & 15;
  const int quad = lane >> 4;
  #pragma unroll
  for (int p = 0; p < 2; ++p) {
    const int lin = tid + p * 256;
    const int r = lin >> 3, g = lin & 7;
    const int fi = (r >> 4) * 128 + g * 16 + (r & 15);
    QP[PG(fi)] = *(const half8*)(q_ + bhoff + (size_t)(q0 + r) * 64 + g * 8);
  }
  __syncthreads();
  half8 qf[4][2];
  #pragma unroll
  for (int ns = 0; ns < 4; ++ns) {
    const int gq = ns * 8 + quad;
    qf[ns][0] = QP[gq * 17 + l15];
    qf[ns][1] = QP[(gq + 4) * 17 + l15];
  }
  float4v oacc[4];
  float lsw[4] = {0.f, 0.f, 0.f, 0.f};
  #pragma unroll
  for (int ns = 0; ns < 4; ++ns) oacc[ns] = (float4v){0.f, 0.f, 0.f, 0.f};
  for (int kc = 0; kc < SLEN; kc += 64) {
    __syncthreads();
    #pragma unroll
    for (int p = 0; p < 2; ++p) {
      const int lin = tid + p * 256;
      const int r = lin >> 3, g = lin & 7;
      const int fi = PG((r >> 4) * 128 + g * 16 + (r & 15));
      Ks[fi] = *(const half8*)(k_ + bhoff + (size_t)(kc + r) * 64 + g * 8);
      Vs[fi] = *(const half8*)(vt + bhoff + (size_t)r * 512 + kc + g * 8);
    }
    if (tid < 128)
      Ms[tid >> 1][tid & 1] =
          pk[((size_t)((bh >> 2) << 9) + q0 + (tid >> 1)) * 16 + (kc >> 5) + (tid & 1)];
    __syncthreads();
    const int ga0 = (w * 8 + quad) * 17 + l15;
    const int ga1 = (w * 8 + quad + 4) * 17 + l15;
    const half8 ah0 = Ks[ga0], ah1 = Ks[ga1];
    #pragma unroll
    for (int ns = 0; ns < 4; ++ns) {
      float4v s = (float4v){0.f, 0.f, 0.f, 0.f};
      s = MFMA16(ah0, qf[ns][0], s);
      s = MFMA16(ah1, qf[ns][1], s);
      const int q = ns * 16 + l15;
      const unsigned long long mrow = *(const unsigned long long*)&Ms[q][0];
      const unsigned mbits = (unsigned)(mrow >> (w * 16 + quad * 4)) & 15u;
      half4 h4;
      #pragma unroll
      for (int r = 0; r < 4; ++r) {
        const float pe = ((mbits >> r) & 1u) ? __expf(s[r] * 0.125f) : 0.f;
        h4[r] = (_Float16)pe;
        lsw[ns] += pe;
      }
      const int hb = ((ns * 8 + w * 2 + (quad >> 1)) * 17 + l15) * 8 + (quad & 1) * 4;
      *(half4*)((_Float16*)QP + hb) = h4;
    }
    __syncthreads();
    const half8 vh0 = Vs[ga0], vh1 = Vs[ga1];
    #pragma unroll
    for (int ns = 0; ns < 4; ++ns) {
      const int pb0 = (ns * 8 + quad) * 17 + l15;
      const int pb1 = (ns * 8 + quad + 4) * 17 + l15;
      oacc[ns] = MFMA16(vh0, QP[pb0], oacc[ns]);
      oacc[ns] = MFMA16(vh1, QP[pb1], oacc[ns]);
    }
  }
  #pragma unroll
  for (int ns = 0; ns < 4; ++ns) {
    lsw[ns] += __shfl_xor(lsw[ns], 16);
    lsw[ns] += __shfl_xor(lsw[ns], 32);
  }
  __syncthreads();
  if (quad == 0) {
    #pragma unroll
    for (int ns = 0; ns < 4; ++ns) Ps[w][ns * 16 + l15] = lsw[ns];
  }
  __syncthreads();
  if (tid < 64) lsum[tid] = Ps[0][tid] + Ps[1][tid] + Ps[2][tid] + Ps[3][tid];
  __syncthreads();
  // epilogue: restage O tile [64 q][64 d] in LDS (stride 68), full-line stores
  const int b = bh >> 2, h = bh & 3;
  _Float16* Ot = (_Float16*)Ks;                 // 64*68 = 4352 halfs, fits exactly
  #pragma unroll
  for (int ns = 0; ns < 4; ++ns) {
    const int q = ns * 16 + l15;
    const float inv = 1.0f / lsum[q];
    half4 h4;
    #pragma unroll
    for (int r = 0; r < 4; ++r) h4[r] = (_Float16)(oacc[ns][r] * inv);
    *(half4*)&Ot[q * 68 + w * 16 + quad * 4] = h4;
  }
  __syncthreads();
  #pragma unroll
  for (int e = 0; e < 2; ++e) {
    const int idx = tid + e * 256;
    const int qq = idx >> 3, g = idx & 7;
    *(half8*)(o + ((size_t)(b * SLEN + q0 + qq)) * DMOD + h * HDIM + g * 8) =
        *(const half8*)&Ot[qq * 68 + g * 8];
  }
}

// ---------------- fused layer norm + zero invalid + triangular pooling ----------
// grid (BSZ, 8): batch x s-chunk of 64 rows; wave per row, 16 rows/wave.
__global__ __launch_bounds__(256) void k_lnpool(
    const float* __restrict__ Y, const int* __restrict__ lengths,
    const float* __restrict__ g, const float* __restrict__ bb,
    float* __restrict__ Up) {
  const int b = blockIdx.x;
  const int c = blockIdx.y;
  const int tid = threadIdx.x;
  const int w = tid >> 6;
  const int lane = tid & 63;
  __shared__ float Pl[4][4][DMOD];              // [wave][bin][d]
  const int len = lengths[b];
  const float inv4 = 4.0f / (float)len;
  float gg[4], bv[4];
  *(float4*)gg = *(const float4*)(g + lane * 4);
  *(float4*)bv = *(const float4*)(bb + lane * 4);
  float a[4][4] = {};                           // [bin][d-sub]
  for (int t = 0; t < 16; ++t) {
    const int r = c * 64 + t * 4 + w;           // global s row
    float v[4];
    *(float4*)v = *(const float4*)(Y + ((size_t)b * SLEN + r) * DMOD + lane * 4);
    float sum = v[0] + v[1] + v[2] + v[3];
    float sq = v[0] * v[0] + v[1] * v[1] + v[2] * v[2] + v[3] * v[3];
    #pragma unroll
    for (int off = 32; off > 0; off >>= 1) {
      sum += __shfl_xor(sum, off);
      sq += __shfl_xor(sq, off);
    }
    const float mu = sum * (1.0f / DMOD);
    const float inv = rsqrtf(sq * (1.0f / DMOD) - mu * mu + 1e-5f);
    const bool valid = r < len;
    float ov[4];
    #pragma unroll
    for (int i = 0; i < 4; ++i)
      ov[i] = valid ? ((v[i] - mu) * inv * gg[i] + bv[i]) : 0.f;
    const float sv = (float)(r + 1) * inv4;
    #pragma unroll
    for (int m = 0; m < 4; ++m) {
      const float tm = 1.0f - fabsf(sv - (float)(m + 1)) * 0.25f;
      const float t2 = tm * tm;
      #pragma unroll
      for (int i = 0; i < 4; ++i) a[m][i] += t2 * ov[i];
    }
  }
  #pragma unroll
  for (int m = 0; m < 4; ++m)
    *(float4*)&Pl[w][m][lane * 4] = *(float4*)a[m];
  __syncthreads();
  // reduce 4 waves: 1024 (bin,d) entries over 256 threads
  #pragma unroll
  for (int e = 0; e < 4; ++e) {
    const int idx = tid + e * 256;              // = m*256 + d
    const int m = idx >> 8, d = idx & 255;
    const float s = Pl[0][m][d] + Pl[1][m][d] + Pl[2][m][d] + Pl[3][m][d];
    Up[(((size_t)b * 8 + c) * 4 + m) * DMOD + d] = s;
  }
}

// ---------------- final [32,1024] @ [1024,2]^T + bias (sums 8 chunk partials) ---
__global__ __launch_bounds__(256) void k_out(
    const float* __restrict__ Up, const float* __restrict__ ow,
    const float* __restrict__ ob, float* __restrict__ out) {
  const int tid = threadIdx.x;
  const int pair = tid >> 2;
  const int part = tid & 3;                     // bin m
  const int b = pair >> 1, i = pair & 1;
  const float* wb = ow + (size_t)i * 1024 + part * DMOD;
  float acc = 0.f;
  for (int d = 0; d < DMOD; d += 4) {
    float4 s = {0.f, 0.f, 0.f, 0.f};
    #pragma unroll
    for (int c = 0; c < 8; ++c) {
      const float4 u = *(const float4*)(Up + (((size_t)b * 8 + c) * 4 + part) * DMOD + d);
      s.x += u.x; s.y += u.y; s.z += u.z; s.w += u.w;
    }
    const float4 wv = *(const float4*)(wb + d);
    acc += s.x * wv.x + s.y * wv.y + s.z * wv.z + s.w * wv.w;
  }
  acc += __shfl_xor(acc, 1);
  acc += __shfl_xor(acc, 2);
  if (part == 0) out[b * 2 + i] = acc + ob[i];
}

extern "C" void kernel_launch(void* const* d_in, const int* in_sizes, int n_in,
                              void* d_out, int out_size, void* d_ws, size_t ws_size,
                              hipStream_t stream) {
  const int* seqs     = (const int*)d_in[0];
  const int* masks    = (const int*)d_in[1];
  const int* lengths  = (const int*)d_in[2];
  const float* emb    = (const float*)d_in[5];
  const float* bias   = (const float*)d_in[6];
  const float* pe     = (const float*)d_in[7];
  const float* Wq     = (const float*)d_in[8];
  const float* Wk     = (const float*)d_in[9];
  const float* Wv     = (const float*)d_in[10];
  const float* Wfc    = (const float*)d_in[11];
  const float* ln_g   = (const float*)d_in[12];
  const float* ln_b   = (const float*)d_in[13];
  const float* out_w  = (const float*)d_in[14];
  const float* out_b  = (const float*)d_in[15];
  float* outp = (float*)d_out;

  const size_t NE = (size_t)BSZ * SLEN * DMOD;   // 4,194,304
  _Float16* q = (_Float16*)d_ws;
  _Float16* k = q + NE;
  _Float16* v = k + NE;
  _Float16* vt = v + NE;
  _Float16* x = vt + NE;
  _Float16* o = x + NE;
  _Float16* wh = o + NE;                         // 4*65536 halfs
  unsigned int* pk = (unsigned int*)(wh + 4 * 65536);
  float* Up = (float*)(pk + BSZ * SLEN * 16);    // [32][8][4][256] fp32 = 1 MB
  float* y = (float*)q;                          // alias: q,k dead after attn (16.7 MB)

  k_embed<<<BSZ * SLEN / 4, 256, 0, stream>>>(seqs, lengths, emb, bias, pe, x);
  k_wsplit<<<dim3(32, 4), 256, 0, stream>>>(Wq, Wk, Wv, Wfc, wh);
  k_maskpack<<<BSZ * SLEN, 256, 0, stream>>>(masks, pk);
  k_gemm_qkv<<<dim3(128, 2, 3), 256, 0, stream>>>(x, wh, q, k, v);
  k_vt<<<dim3(BSZ * NH, 2), 256, 0, stream>>>(v, vt);
  k_attn<<<dim3(BSZ * NH, SLEN / 64), 256, 0, stream>>>(q, k, vt, pk, o);
  k_gemm_fc<<<dim3(128, 2), 256, 0, stream>>>(o, wh + 3 * 65536, y, x);
  k_lnpool<<<dim3(BSZ, 8), 256, 0, stream>>>(y, lengths, ln_g, ln_b, Up);
  k_out<<<1, 256, 0, stream>>>(Up, out_w, out_b, outp);
}

// Round 14
// 259.328 us; speedup vs baseline: 1.2403x; 1.2403x over previous
//
#include <hip/hip_runtime.h>

#define BSZ 32
#define SLEN 512
#define CLEN 20
#define DMOD 256
#define NH 4
#define HDIM 64

typedef _Float16 half8 __attribute__((ext_vector_type(8)));
typedef _Float16 half4 __attribute__((ext_vector_type(4)));
typedef float float4v __attribute__((ext_vector_type(4)));

#define MFMA16(a, b, c) __builtin_amdgcn_mfma_f32_16x16x32_f16(a, b, c, 0, 0, 0)
// padded half8 index: groups of 16 half8 get stride 17 (breaks 256B-stride conflicts)
#define PG(fi) ((((fi) >> 4) * 17) + ((fi) & 15))

// ---------------- embedding sum + positional encoding -> fp16 ------------------
__global__ __launch_bounds__(256) void k_embed(
    const int* __restrict__ seqs, const int* __restrict__ lengths,
    const float* __restrict__ emb, const float* __restrict__ bias,
    const float* __restrict__ pe, _Float16* __restrict__ x) {
  const int row0 = blockIdx.x * 4;
  const int sub = threadIdx.x >> 6;
  const int lane = threadIdx.x & 63;
  const int row = row0 + sub;
  const int b = row >> 9, s = row & 511;
  __shared__ int codes[4][CLEN];
  if (threadIdx.x < 4 * CLEN)
    codes[threadIdx.x / CLEN][threadIdx.x % CLEN] = seqs[row0 * CLEN + threadIdx.x];
  __syncthreads();
  const int pos = (s < lengths[b]) ? (s + 1) : 0;
  const int d = lane * 4;
  float4 acc = *(const float4*)(bias + d);
  const float4 pv = *(const float4*)(pe + (size_t)pos * DMOD + d);
  acc.x += pv.x; acc.y += pv.y; acc.z += pv.z; acc.w += pv.w;
  #pragma unroll
  for (int c = 0; c < CLEN; ++c) {
    const float4 ev = *(const float4*)(emb + (size_t)codes[sub][c] * DMOD + d);
    acc.x += ev.x; acc.y += ev.y; acc.z += ev.z; acc.w += ev.w;
  }
  half4 hv;
  hv[0] = (_Float16)acc.x; hv[1] = (_Float16)acc.y;
  hv[2] = (_Float16)acc.z; hv[3] = (_Float16)acc.w;
  *(half4*)(x + (size_t)row * DMOD + d) = hv;
}

// ---------------- cast 4 weight matrices [256x256] fp32 -> fp16 ----------------
__global__ __launch_bounds__(256) void k_wsplit(
    const float* __restrict__ W0, const float* __restrict__ W1,
    const float* __restrict__ W2, const float* __restrict__ W3,
    _Float16* __restrict__ wh) {
  const int z = blockIdx.y;
  const float* W = (z == 0) ? W0 : (z == 1) ? W1 : (z == 2) ? W2 : W3;
  const int idx = (blockIdx.x * 256 + threadIdx.x) * 8;
  float v[8];
  *(float4*)v = *(const float4*)(W + idx);
  *(float4*)(v + 4) = *(const float4*)(W + idx + 4);
  half8 h;
  #pragma unroll
  for (int i = 0; i < 8; ++i) h[i] = (_Float16)v[i];
  *(half8*)(wh + (size_t)z * 65536 + idx) = h;
}

// ---------------- bit-pack attention mask: [32,512,512] int -> [32,512,16] u32 ----
__global__ __launch_bounds__(256) void k_maskpack(
    const int* __restrict__ masks, unsigned int* __restrict__ pk) {
  const int bq = blockIdx.x;
  const int wv = threadIdx.x >> 6;
  const int lane = threadIdx.x & 63;
  #pragma unroll
  for (int p = 0; p < 2; ++p) {
    const int chunk = wv + p * 4;
    const int m = masks[(size_t)bq * SLEN + chunk * 64 + lane];
    const unsigned long long bal = __ballot(m != 0);
    if (lane == 0) {
      pk[(size_t)bq * 16 + chunk * 2]     = (unsigned int)bal;
      pk[(size_t)bq * 16 + chunk * 2 + 1] = (unsigned int)(bal >> 32);
    }
  }
}

// ---------------- QKV GEMM: fp16 MFMA, prefetch, vectorized epilogue ------------
__global__ __launch_bounds__(256) void k_gemm_qkv(
    const _Float16* __restrict__ A, const _Float16* __restrict__ Wb,
    _Float16* __restrict__ q, _Float16* __restrict__ k, _Float16* __restrict__ v) {
  const int z = blockIdx.z;
  _Float16* Cb = (z == 0) ? q : (z == 1) ? k : v;
  const _Float16* w_ = Wb + (size_t)z * 65536;
  const int m0 = blockIdx.x * 128;
  const int n0 = blockIdx.y * 128;
  const int tid = threadIdx.x;
  const int lane = tid & 63;
  const int w = tid >> 6;
  const int wm = (w >> 1) * 4;
  const int wn = (w & 1) * 4;
  __shared__ _Float16 smem[8704];               // 17 KB: staging; epilogue reuse
  half8* As = (half8*)(smem);
  half8* Ws = (half8*)(smem + 4096);
  float4v acc[4][4];
  #pragma unroll
  for (int i = 0; i < 4; ++i)
    #pragma unroll
    for (int j = 0; j < 4; ++j)
      acc[i][j] = (float4v){0.f, 0.f, 0.f, 0.f};
  int li_[2]; size_t ga_[2], gw_[2];
  #pragma unroll
  for (int p = 0; p < 2; ++p) {
    const int c = tid + p * 256;
    const int r = c & 127, qd = c >> 7;
    li_[p] = (r >> 4) * 64 + qd * 16 + (r & 15);
    ga_[p] = (size_t)(m0 + r) * DMOD + qd * 8;
    gw_[p] = (size_t)(n0 + r) * DMOD + qd * 8;
  }
  half8 pa[2], pw[2];
  #pragma unroll
  for (int p = 0; p < 2; ++p) {
    pa[p] = *(const half8*)(A + ga_[p]);
    pw[p] = *(const half8*)(w_ + gw_[p]);
  }
  for (int k0 = 0; k0 < DMOD; k0 += 32) {
    #pragma unroll
    for (int p = 0; p < 2; ++p) {
      As[li_[p]] = pa[p];
      Ws[li_[p]] = pw[p];
    }
    __syncthreads();
    if (k0 + 32 < DMOD) {
      #pragma unroll
      for (int p = 0; p < 2; ++p) {
        pa[p] = *(const half8*)(A + ga_[p] + k0 + 32);
        pw[p] = *(const half8*)(w_ + gw_[p] + k0 + 32);
      }
    }
    half8 af[4], wf[4];
    #pragma unroll
    for (int i = 0; i < 4; ++i) {
      af[i] = As[(wm + i) * 64 + lane];
      wf[i] = Ws[(wn + i) * 64 + lane];
    }
    #pragma unroll
    for (int i = 0; i < 4; ++i)
      #pragma unroll
      for (int j = 0; j < 4; ++j)
        acc[i][j] = MFMA16(af[i], wf[j], acc[i][j]);
    __syncthreads();
  }
  const int cr = (lane >> 4) * 4;
  const int cc = lane & 15;
  _Float16* Eh = smem;
  #pragma unroll
  for (int ip = 0; ip < 4; ++ip) {
    #pragma unroll
    for (int j = 0; j < 4; ++j) {
      const int col = (wn + j) * 16 + cc;
      #pragma unroll
      for (int r = 0; r < 4; ++r)
        Eh[((w >> 1) * 16 + cr + r) * 136 + col] = (_Float16)acc[ip][j][r];
    }
    __syncthreads();
    #pragma unroll
    for (int e = 0; e < 2; ++e) {
      const int idx = tid + e * 256;
      const int lr = idx >> 4;
      const int cg = idx & 15;
      const int gr = m0 + (lr >> 4) * 64 + ip * 16 + (lr & 15);
      *(half8*)(Cb + (size_t)gr * DMOD + n0 + cg * 8) =
          *(const half8*)&Eh[lr * 136 + cg * 8];
    }
    __syncthreads();
  }
}

// ---------------- per-bh transpose: v[bh][s][d] -> vt[bh][d][s] -----------------
__global__ __launch_bounds__(256) void k_vt(
    const _Float16* __restrict__ v, _Float16* __restrict__ vt) {
  const int bh = blockIdx.x;
  const size_t off = (size_t)bh * 32768;
  __shared__ _Float16 Th[64][66];
  const int tid = threadIdx.x;
  const int c0 = blockIdx.y * 4;
  for (int c = c0; c < c0 + 4; ++c) {
    const int sc = c * 64;
    #pragma unroll
    for (int p = 0; p < 2; ++p) {
      const int lin = tid + p * 256;
      const int r = lin >> 3, g = lin & 7;
      *(half8*)&Th[r][g * 8] = *(const half8*)(v + off + (size_t)(sc + r) * 64 + g * 8);
    }
    __syncthreads();
    #pragma unroll
    for (int p = 0; p < 2; ++p) {
      const int lin = tid + p * 256;
      const int d = lin >> 3, sg = lin & 7;
      half8 hv;
      #pragma unroll
      for (int j = 0; j < 8; ++j) hv[j] = Th[sg * 8 + j][d];
      *(half8*)(vt + off + (size_t)d * 512 + sc + sg * 8) = hv;
    }
    __syncthreads();
  }
}

// ---------------- FC GEMM (fp32 out + fp16 residual), fp16 MFMA -----------------
__global__ __launch_bounds__(256) void k_gemm_fc(
    const _Float16* __restrict__ A, const _Float16* __restrict__ w_,
    float* __restrict__ C, const _Float16* __restrict__ res) {
  const int m0 = blockIdx.x * 128;
  const int n0 = blockIdx.y * 128;
  const int tid = threadIdx.x;
  const int lane = tid & 63;
  const int w = tid >> 6;
  const int wm = (w >> 1) * 4;
  const int wn = (w & 1) * 4;
  __shared__ half8 As[512], Ws[512];
  float4v acc[4][4];
  #pragma unroll
  for (int i = 0; i < 4; ++i)
    #pragma unroll
    for (int j = 0; j < 4; ++j)
      acc[i][j] = (float4v){0.f, 0.f, 0.f, 0.f};
  int li_[2]; size_t ga_[2], gw_[2];
  #pragma unroll
  for (int p = 0; p < 2; ++p) {
    const int c = tid + p * 256;
    const int r = c & 127, qd = c >> 7;
    li_[p] = (r >> 4) * 64 + qd * 16 + (r & 15);
    ga_[p] = (size_t)(m0 + r) * DMOD + qd * 8;
    gw_[p] = (size_t)(n0 + r) * DMOD + qd * 8;
  }
  half8 pa[2], pw[2];
  #pragma unroll
  for (int p = 0; p < 2; ++p) {
    pa[p] = *(const half8*)(A + ga_[p]);
    pw[p] = *(const half8*)(w_ + gw_[p]);
  }
  for (int k0 = 0; k0 < DMOD; k0 += 32) {
    #pragma unroll
    for (int p = 0; p < 2; ++p) {
      As[li_[p]] = pa[p];
      Ws[li_[p]] = pw[p];
    }
    __syncthreads();
    if (k0 + 32 < DMOD) {
      #pragma unroll
      for (int p = 0; p < 2; ++p) {
        pa[p] = *(const half8*)(A + ga_[p] + k0 + 32);
        pw[p] = *(const half8*)(w_ + gw_[p] + k0 + 32);
      }
    }
    half8 af[4], wf[4];
    #pragma unroll
    for (int i = 0; i < 4; ++i) {
      af[i] = As[(wm + i) * 64 + lane];
      wf[i] = Ws[(wn + i) * 64 + lane];
    }
    #pragma unroll
    for (int i = 0; i < 4; ++i)
      #pragma unroll
      for (int j = 0; j < 4; ++j)
        acc[i][j] = MFMA16(af[i], wf[j], acc[i][j]);
    __syncthreads();
  }
  const int cr = (lane >> 4) * 4;
  const int cc = lane & 15;
  #pragma unroll
  for (int i = 0; i < 4; ++i) {
    const int gm = m0 + (wm + i) * 16 + cr;
    #pragma unroll
    for (int j = 0; j < 4; ++j) {
      const int gc = n0 + (wn + j) * 16 + cc;
      #pragma unroll
      for (int r = 0; r < 4; ++r) {
        const size_t flat = (size_t)(gm + r) * DMOD + gc;
        C[flat] = acc[i][j][r] + (float)res[flat];
      }
    }
  }
}

// ---------------- MFMA attention per (bh, q-tile of 64), fp16 -------------------
__global__ __launch_bounds__(256, 4) void k_attn(
    const _Float16* __restrict__ q_, const _Float16* __restrict__ k_,
    const _Float16* __restrict__ vt, const unsigned int* __restrict__ pk,
    _Float16* __restrict__ o) {
  const int bh = blockIdx.x;
  const int q0 = blockIdx.y * 64;
  const size_t bhoff = (size_t)bh * 32768;
  __shared__ half8 QP[544];                     // Q staging, then P
  __shared__ half8 Ks[544], Vs[544];            // Ks reused as O-tile in epilogue
  __shared__ unsigned long long Ms64[64];       // 8-byte aligned mask rows
  __shared__ float Ps[4][64];
  __shared__ float lsum[64];
  const int tid = threadIdx.x;
  const int w = tid >> 6;
  const int lane = tid & 63;
  const int l15 = lane & 15;
  const int quad = lane >> 4;
  #pragma unroll
  for (int p = 0; p < 2; ++p) {
    const int lin = tid + p * 256;
    const int r = lin >> 3, g = lin & 7;
    const int fi = (r >> 4) * 128 + g * 16 + (r & 15);
    QP[PG(fi)] = *(const half8*)(q_ + bhoff + (size_t)(q0 + r) * 64 + g * 8);
  }
  __syncthreads();
  half8 qf[4][2];
  #pragma unroll
  for (int ns = 0; ns < 4; ++ns) {
    const int gq = ns * 8 + quad;
    qf[ns][0] = QP[gq * 17 + l15];
    qf[ns][1] = QP[(gq + 4) * 17 + l15];
  }
  float4v oacc[4];
  float lsw[4] = {0.f, 0.f, 0.f, 0.f};
  #pragma unroll
  for (int ns = 0; ns < 4; ++ns) oacc[ns] = (float4v){0.f, 0.f, 0.f, 0.f};
  for (int kc = 0; kc < SLEN; kc += 64) {
    __syncthreads();
    #pragma unroll
    for (int p = 0; p < 2; ++p) {
      const int lin = tid + p * 256;
      const int r = lin >> 3, g = lin & 7;
      const int fi = PG((r >> 4) * 128 + g * 16 + (r & 15));
      Ks[fi] = *(const half8*)(k_ + bhoff + (size_t)(kc + r) * 64 + g * 8);
      Vs[fi] = *(const half8*)(vt + bhoff + (size_t)r * 512 + kc + g * 8);
    }
    if (tid < 128)
      ((unsigned int*)Ms64)[tid] =
          pk[((size_t)((bh >> 2) << 9) + q0 + (tid >> 1)) * 16 + (kc >> 5) + (tid & 1)];
    __syncthreads();
    const int ga0 = (w * 8 + quad) * 17 + l15;
    const int ga1 = (w * 8 + quad + 4) * 17 + l15;
    const half8 ah0 = Ks[ga0], ah1 = Ks[ga1];
    #pragma unroll
    for (int ns = 0; ns < 4; ++ns) {
      float4v s = (float4v){0.f, 0.f, 0.f, 0.f};
      s = MFMA16(ah0, qf[ns][0], s);
      s = MFMA16(ah1, qf[ns][1], s);
      const int q = ns * 16 + l15;
      const unsigned long long mrow = Ms64[q];
      const unsigned mbits = (unsigned)(mrow >> (w * 16 + quad * 4)) & 15u;
      half4 h4;
      #pragma unroll
      for (int r = 0; r < 4; ++r) {
        const float pe = ((mbits >> r) & 1u) ? __expf(s[r] * 0.125f) : 0.f;
        h4[r] = (_Float16)pe;
        lsw[ns] += pe;
      }
      const int hb = ((ns * 8 + w * 2 + (quad >> 1)) * 17 + l15) * 8 + (quad & 1) * 4;
      *(half4*)((_Float16*)QP + hb) = h4;
    }
    __syncthreads();
    const half8 vh0 = Vs[ga0], vh1 = Vs[ga1];
    #pragma unroll
    for (int ns = 0; ns < 4; ++ns) {
      const int pb0 = (ns * 8 + quad) * 17 + l15;
      const int pb1 = (ns * 8 + quad + 4) * 17 + l15;
      oacc[ns] = MFMA16(vh0, QP[pb0], oacc[ns]);
      oacc[ns] = MFMA16(vh1, QP[pb1], oacc[ns]);
    }
  }
  #pragma unroll
  for (int ns = 0; ns < 4; ++ns) {
    lsw[ns] += __shfl_xor(lsw[ns], 16);
    lsw[ns] += __shfl_xor(lsw[ns], 32);
  }
  __syncthreads();
  if (quad == 0) {
    #pragma unroll
    for (int ns = 0; ns < 4; ++ns) Ps[w][ns * 16 + l15] = lsw[ns];
  }
  __syncthreads();
  if (tid < 64) lsum[tid] = Ps[0][tid] + Ps[1][tid] + Ps[2][tid] + Ps[3][tid];
  __syncthreads();
  // epilogue: restage O tile [64 q][64 d] in LDS (stride 68), full-line stores
  const int b = bh >> 2, h = bh & 3;
  _Float16* Ot = (_Float16*)Ks;                 // 64*68 = 4352 halfs, fits exactly
  #pragma unroll
  for (int ns = 0; ns < 4; ++ns) {
    const int q = ns * 16 + l15;
    const float inv = 1.0f / lsum[q];
    half4 h4;
    #pragma unroll
    for (int r = 0; r < 4; ++r) h4[r] = (_Float16)(oacc[ns][r] * inv);
    *(half4*)&Ot[q * 68 + w * 16 + quad * 4] = h4;
  }
  __syncthreads();
  #pragma unroll
  for (int e = 0; e < 2; ++e) {
    const int idx = tid + e * 256;
    const int qq = idx >> 3, g = idx & 7;
    *(half8*)(o + ((size_t)(b * SLEN + q0 + qq)) * DMOD + h * HDIM + g * 8) =
        *(const half8*)&Ot[qq * 68 + g * 8];
  }
}

// ---------------- fused layer norm + zero invalid + triangular pooling ----------
__global__ __launch_bounds__(256) void k_lnpool(
    const float* __restrict__ Y, const int* __restrict__ lengths,
    const float* __restrict__ g, const float* __restrict__ bb,
    float* __restrict__ Up) {
  const int b = blockIdx.x;
  const int c = blockIdx.y;
  const int tid = threadIdx.x;
  const int w = tid >> 6;
  const int lane = tid & 63;
  __shared__ float Pl[4][4][DMOD];              // [wave][bin][d]
  const int len = lengths[b];
  const float inv4 = 4.0f / (float)len;
  float gg[4], bv[4];
  *(float4*)gg = *(const float4*)(g + lane * 4);
  *(float4*)bv = *(const float4*)(bb + lane * 4);
  float a[4][4] = {};                           // [bin][d-sub]
  for (int t = 0; t < 16; ++t) {
    const int r = c * 64 + t * 4 + w;
    float v[4];
    *(float4*)v = *(const float4*)(Y + ((size_t)b * SLEN + r) * DMOD + lane * 4);
    float sum = v[0] + v[1] + v[2] + v[3];
    float sq = v[0] * v[0] + v[1] * v[1] + v[2] * v[2] + v[3] * v[3];
    #pragma unroll
    for (int off = 32; off > 0; off >>= 1) {
      sum += __shfl_xor(sum, off);
      sq += __shfl_xor(sq, off);
    }
    const float mu = sum * (1.0f / DMOD);
    const float inv = rsqrtf(sq * (1.0f / DMOD) - mu * mu + 1e-5f);
    const bool valid = r < len;
    float ov[4];
    #pragma unroll
    for (int i = 0; i < 4; ++i)
      ov[i] = valid ? ((v[i] - mu) * inv * gg[i] + bv[i]) : 0.f;
    const float sv = (float)(r + 1) * inv4;
    #pragma unroll
    for (int m = 0; m < 4; ++m) {
      const float tm = 1.0f - fabsf(sv - (float)(m + 1)) * 0.25f;
      const float t2 = tm * tm;
      #pragma unroll
      for (int i = 0; i < 4; ++i) a[m][i] += t2 * ov[i];
    }
  }
  #pragma unroll
  for (int m = 0; m < 4; ++m)
    *(float4*)&Pl[w][m][lane * 4] = *(float4*)a[m];
  __syncthreads();
  #pragma unroll
  for (int e = 0; e < 4; ++e) {
    const int idx = tid + e * 256;
    const int m = idx >> 8, d = idx & 255;
    const float s = Pl[0][m][d] + Pl[1][m][d] + Pl[2][m][d] + Pl[3][m][d];
    Up[(((size_t)b * 8 + c) * 4 + m) * DMOD + d] = s;
  }
}

// ---------------- final [32,1024] @ [1024,2]^T + bias, one block per batch ------
__global__ __launch_bounds__(256) void k_out(
    const float* __restrict__ Up, const float* __restrict__ ow,
    const float* __restrict__ ob, float* __restrict__ out) {
  const int b = blockIdx.x;
  const int tid = threadIdx.x;
  const int w = tid >> 6;
  const int lane = tid & 63;
  __shared__ float rr[8];
  float4 s = {0.f, 0.f, 0.f, 0.f};
  #pragma unroll
  for (int c = 0; c < 8; ++c) {
    const float4 u = *(const float4*)(Up + ((size_t)b * 8 + c) * 1024 + tid * 4);
    s.x += u.x; s.y += u.y; s.z += u.z; s.w += u.w;
  }
  const float4 w0 = *(const float4*)(ow + tid * 4);
  const float4 w1 = *(const float4*)(ow + 1024 + tid * 4);
  float acc0 = s.x * w0.x + s.y * w0.y + s.z * w0.z + s.w * w0.w;
  float acc1 = s.x * w1.x + s.y * w1.y + s.z * w1.z + s.w * w1.w;
  #pragma unroll
  for (int off = 32; off > 0; off >>= 1) {
    acc0 += __shfl_xor(acc0, off);
    acc1 += __shfl_xor(acc1, off);
  }
  if (lane == 0) { rr[w] = acc0; rr[4 + w] = acc1; }
  __syncthreads();
  if (tid == 0) {
    out[b * 2 + 0] = rr[0] + rr[1] + rr[2] + rr[3] + ob[0];
    out[b * 2 + 1] = rr[4] + rr[5] + rr[6] + rr[7] + ob[1];
  }
}

extern "C" void kernel_launch(void* const* d_in, const int* in_sizes, int n_in,
                              void* d_out, int out_size, void* d_ws, size_t ws_size,
                              hipStream_t stream) {
  const int* seqs     = (const int*)d_in[0];
  const int* masks    = (const int*)d_in[1];
  const int* lengths  = (const int*)d_in[2];
  const float* emb    = (const float*)d_in[5];
  const float* bias   = (const float*)d_in[6];
  const float* pe     = (const float*)d_in[7];
  const float* Wq     = (const float*)d_in[8];
  const float* Wk     = (const float*)d_in[9];
  const float* Wv     = (const float*)d_in[10];
  const float* Wfc    = (const float*)d_in[11];
  const float* ln_g   = (const float*)d_in[12];
  const float* ln_b   = (const float*)d_in[13];
  const float* out_w  = (const float*)d_in[14];
  const float* out_b  = (const float*)d_in[15];
  float* outp = (float*)d_out;

  const size_t NE = (size_t)BSZ * SLEN * DMOD;   // 4,194,304
  _Float16* q = (_Float16*)d_ws;
  _Float16* k = q + NE;
  _Float16* v = k + NE;
  _Float16* vt = v + NE;
  _Float16* x = vt + NE;
  _Float16* o = x + NE;
  _Float16* wh = o + NE;                         // 4*65536 halfs
  unsigned int* pk = (unsigned int*)(wh + 4 * 65536);
  float* Up = (float*)(pk + BSZ * SLEN * 16);    // [32][8][4][256] fp32 = 1 MB
  float* y = (float*)q;                          // alias: q,k dead after attn

  k_embed<<<BSZ * SLEN / 4, 256, 0, stream>>>(seqs, lengths, emb, bias, pe, x);
  k_wsplit<<<dim3(32, 4), 256, 0, stream>>>(Wq, Wk, Wv, Wfc, wh);
  k_maskpack<<<BSZ * SLEN, 256, 0, stream>>>(masks, pk);
  k_gemm_qkv<<<dim3(128, 2, 3), 256, 0, stream>>>(x, wh, q, k, v);
  k_vt<<<dim3(BSZ * NH, 2), 256, 0, stream>>>(v, vt);
  k_attn<<<dim3(BSZ * NH, SLEN / 64), 256, 0, stream>>>(q, k, vt, pk, o);
  k_gemm_fc<<<dim3(128, 2), 256, 0, stream>>>(o, wh + 3 * 65536, y, x);
  k_lnpool<<<dim3(BSZ, 8), 256, 0, stream>>>(y, lengths, ln_g, ln_b, Up);
  k_out<<<BSZ, 256, 0, stream>>>(Up, out_w, out_b, outp);
}